// Round 1
// baseline (191.633 us; speedup 1.0000x reference)
//
#include <hip/hip_runtime.h>
#include <hip/hip_bf16.h>
#include <math.h>

#define BB 32
#define RR 2000
#define CC 81
#define CM1 80

// ---------------------------------------------------------------------------
// Kernel A: per-(batch, class) column — compact valid entries, sort by
// (score desc, row asc), decode boxes for valid ranks, write dets+sorted_valid.
// ---------------------------------------------------------------------------
__global__ __launch_bounds__(256) void sort_decode_kernel(
    const float* __restrict__ rois,      // (B, R, 5)
    const float* __restrict__ cls,       // (B, R, C)
    const float* __restrict__ bbox,      // (B, R, 4*C)
    float* __restrict__ dets,            // (B, R, 80, 5)
    float* __restrict__ sv)              // (B, R, 80)
{
    __shared__ float ssc[2048];
    __shared__ int   sidx[2048];
    __shared__ int   scount;

    const int b   = blockIdx.x / CM1;
    const int j   = blockIdx.x % CM1;     // class-1 index (0..79)
    const int tid = threadIdx.x;
    const int cls_col = j + 1;

    if (tid == 0) scount = 0;
    __syncthreads();

    // Compact valid (score, row) pairs into LDS.
    for (int r = tid; r < RR; r += 256) {
        float s = cls[(size_t)(b * RR + r) * CC + cls_col];
        if (s > 0.1f) {
            int p = atomicAdd(&scount, 1);
            ssc[p]  = s;
            sidx[p] = r;
        }
    }
    __syncthreads();

    const int n = scount;

    if (n > 1) {
        int n2 = 1;
        while (n2 < n) n2 <<= 1;
        // Pad to pow2 with sentinels that sort last.
        for (int i = n + tid; i < n2; i += 256) {
            ssc[i]  = -INFINITY;
            sidx[i] = 0x7FFFFFFF;
        }
        __syncthreads();

        // Bitonic sort, overall descending by (score, -row).
        for (int k = 2; k <= n2; k <<= 1) {
            for (int jj = k >> 1; jj > 0; jj >>= 1) {
                for (int i = tid; i < n2; i += 256) {
                    int ixj = i ^ jj;
                    if (ixj > i) {
                        float si = ssc[i], sx = ssc[ixj];
                        int   ii = sidx[i], ix = sidx[ixj];
                        // "si before sx" in final (descending) order:
                        bool before = (si > sx) || (si == sx && ii < ix);
                        bool doswap = ((i & k) == 0) ? !before : before;
                        if (doswap) {
                            ssc[i] = sx; ssc[ixj] = si;
                            sidx[i] = ix; sidx[ixj] = ii;
                        }
                    }
                }
                __syncthreads();
            }
        }
    }

    // Write all R ranks for this column: valid prefix decoded, rest zero.
    for (int i = tid; i < RR; i += 256) {
        size_t obase = ((size_t)(b * RR + i) * CM1 + j) * 5;
        if (i < n) {
            int   r = sidx[i];
            float s = ssc[i];
            const float* rp = rois + (size_t)(b * RR + r) * 5;
            float x1 = rp[1], y1 = rp[2], x2 = rp[3], y2 = rp[4];
            float w  = x2 - x1 + 1.0f;
            float h  = y2 - y1 + 1.0f;
            float cx = x1 + 0.5f * w;
            float cy = y1 + 0.5f * h;
            const float* dp = bbox + (size_t)(b * RR + r) * (4 * CC) + 4 * cls_col;
            float dx = dp[0] * 0.1f, dy = dp[1] * 0.1f;
            float dw = dp[2] * 0.2f, dh = dp[3] * 0.2f;
            float pcx = dx * w + cx;
            float pcy = dy * h + cy;
            float pw  = expf(dw) * w;
            float ph  = expf(dh) * h;
            float bx1 = fmaxf(pcx - 0.5f * pw, 0.0f);
            float by1 = fmaxf(pcy - 0.5f * ph, 0.0f);
            float bx2 = fmaxf(pcx + 0.5f * pw - 1.0f, 0.0f);
            float by2 = fmaxf(pcy + 0.5f * ph - 1.0f, 0.0f);
            dets[obase + 0] = bx1;
            dets[obase + 1] = by1;
            dets[obase + 2] = bx2;
            dets[obase + 3] = by2;
            dets[obase + 4] = s;
            sv[(size_t)(b * RR + i) * CM1 + j] = 1.0f;
        } else {
            dets[obase + 0] = 0.0f;
            dets[obase + 1] = 0.0f;
            dets[obase + 2] = 0.0f;
            dets[obase + 3] = 0.0f;
            dets[obase + 4] = 0.0f;
            sv[(size_t)(b * RR + i) * CM1 + j] = 0.0f;
        }
    }
}

// ---------------------------------------------------------------------------
// Kernel B: one wave (64 lanes) per row — softmax over 81 classes,
// max_scores = 1/sum(exp(x-max)), pred_labels = first argmax.
// ---------------------------------------------------------------------------
__global__ __launch_bounds__(256) void softmax_kernel(
    const float* __restrict__ cls,   // (B*R, 81)
    float* __restrict__ dist,        // (B*R, 81)
    float* __restrict__ maxs,        // (B*R,)
    float* __restrict__ labels)      // (B*R,)
{
    const int wave = threadIdx.x >> 6;
    const int lane = threadIdx.x & 63;
    const int row  = blockIdx.x * 4 + wave;
    if (row >= BB * RR) return;

    const float* in = cls + (size_t)row * CC;
    float v0 = in[lane];
    float v1 = (lane < CC - 64) ? in[64 + lane] : -INFINITY;

    float m  = v0;
    int   mi = lane;
    if (v1 > m) { m = v1; mi = 64 + lane; }   // strict >, keeps smaller idx on tie

    for (int off = 32; off > 0; off >>= 1) {
        float om  = __shfl_xor(m, off);
        int   omi = __shfl_xor(mi, off);
        if (om > m || (om == m && omi < mi)) { m = om; mi = omi; }
    }

    float e0 = expf(v0 - m);
    float e1 = (lane < CC - 64) ? expf(v1 - m) : 0.0f;
    float s  = e0 + e1;
    for (int off = 32; off > 0; off >>= 1) s += __shfl_xor(s, off);

    float inv = 1.0f / s;
    float* out = dist + (size_t)row * CC;
    out[lane] = e0 * inv;
    if (lane < CC - 64) out[64 + lane] = e1 * inv;
    if (lane == 0) {
        maxs[row]   = inv;        // max of softmax = exp(0)/sum
        labels[row] = (float)mi;
    }
}

extern "C" void kernel_launch(void* const* d_in, const int* in_sizes, int n_in,
                              void* d_out, int out_size, void* d_ws, size_t ws_size,
                              hipStream_t stream) {
    const float* rois = (const float*)d_in[0];   // B*R*5
    const float* cls  = (const float*)d_in[1];   // B*R*81
    const float* bbox = (const float*)d_in[2];   // B*R*324

    float* out = (float*)d_out;
    // Output layout (concatenated flat, return order):
    const size_t dets_off = 0;
    const size_t sv_off   = (size_t)BB * RR * CM1 * 5;         // 25,600,000
    const size_t dist_off = sv_off + (size_t)BB * RR * CM1;    // 30,720,000
    const size_t maxs_off = dist_off + (size_t)BB * RR * CC;   // 35,904,000
    const size_t lab_off  = maxs_off + (size_t)BB * RR;        // 35,968,000

    float* dets   = out + dets_off;
    float* sv     = out + sv_off;
    float* dist   = out + dist_off;
    float* maxs   = out + maxs_off;
    float* labels = out + lab_off;

    sort_decode_kernel<<<BB * CM1, 256, 0, stream>>>(rois, cls, bbox, dets, sv);

    const int rows = BB * RR;
    softmax_kernel<<<(rows + 3) / 4, 256, 0, stream>>>(cls, dist, maxs, labels);
}

// Round 2
// 77.305 us; speedup vs baseline: 2.4789x; 2.4789x over previous
//
#include <hip/hip_runtime.h>
#include <hip/hip_bf16.h>
#include <math.h>

#define BB 32
#define RR 2000
#define CC 81
#define CM1 80

// ---------------------------------------------------------------------------
// Kernel A: per-(batch, class) column — compact valid entries, sort by
// (score desc, row asc), decode boxes for valid ranks, write ONLY the valid
// prefix of dets/sorted_valid (the rest is pre-zeroed by hipMemsetAsync).
// ---------------------------------------------------------------------------
__global__ __launch_bounds__(256) void sort_decode_kernel(
    const float* __restrict__ rois,      // (B, R, 5)
    const float* __restrict__ cls,       // (B, R, C)
    const float* __restrict__ bbox,      // (B, R, 4*C)
    float* __restrict__ dets,            // (B, R, 80, 5)
    float* __restrict__ sv)              // (B, R, 80)
{
    __shared__ float ssc[2048];
    __shared__ int   sidx[2048];
    __shared__ int   scount;

    const int b   = blockIdx.x / CM1;
    const int j   = blockIdx.x % CM1;     // class-1 index (0..79)
    const int tid = threadIdx.x;
    const int cls_col = j + 1;

    if (tid == 0) scount = 0;
    __syncthreads();

    // Compact valid (score, row) pairs into LDS.
    for (int r = tid; r < RR; r += 256) {
        float s = cls[(size_t)(b * RR + r) * CC + cls_col];
        if (s > 0.1f) {
            int p = atomicAdd(&scount, 1);
            ssc[p]  = s;
            sidx[p] = r;
        }
    }
    __syncthreads();

    const int n = scount;

    if (n > 1) {
        int n2 = 1;
        while (n2 < n) n2 <<= 1;
        // Pad to pow2 with sentinels that sort last.
        for (int i = n + tid; i < n2; i += 256) {
            ssc[i]  = -INFINITY;
            sidx[i] = 0x7FFFFFFF;
        }
        __syncthreads();

        // Bitonic sort, overall descending by (score, -row).
        for (int k = 2; k <= n2; k <<= 1) {
            for (int jj = k >> 1; jj > 0; jj >>= 1) {
                for (int i = tid; i < n2; i += 256) {
                    int ixj = i ^ jj;
                    if (ixj > i) {
                        float si = ssc[i], sx = ssc[ixj];
                        int   ii = sidx[i], ix = sidx[ixj];
                        bool before = (si > sx) || (si == sx && ii < ix);
                        bool doswap = ((i & k) == 0) ? !before : before;
                        if (doswap) {
                            ssc[i] = sx; ssc[ixj] = si;
                            sidx[i] = ix; sidx[ixj] = ii;
                        }
                    }
                }
                __syncthreads();
            }
        }
    }

    // Write only the valid prefix (rest pre-zeroed by memset).
    for (int i = tid; i < n; i += 256) {
        size_t obase = ((size_t)(b * RR + i) * CM1 + j) * 5;
        int   r = sidx[i];
        float s = ssc[i];
        const float* rp = rois + (size_t)(b * RR + r) * 5;
        float x1 = rp[1], y1 = rp[2], x2 = rp[3], y2 = rp[4];
        float w  = x2 - x1 + 1.0f;
        float h  = y2 - y1 + 1.0f;
        float cx = x1 + 0.5f * w;
        float cy = y1 + 0.5f * h;
        const float* dp = bbox + (size_t)(b * RR + r) * (4 * CC) + 4 * cls_col;
        float dx = dp[0] * 0.1f, dy = dp[1] * 0.1f;
        float dw = dp[2] * 0.2f, dh = dp[3] * 0.2f;
        float pcx = dx * w + cx;
        float pcy = dy * h + cy;
        float pw  = expf(dw) * w;
        float ph  = expf(dh) * h;
        dets[obase + 0] = fmaxf(pcx - 0.5f * pw, 0.0f);
        dets[obase + 1] = fmaxf(pcy - 0.5f * ph, 0.0f);
        dets[obase + 2] = fmaxf(pcx + 0.5f * pw - 1.0f, 0.0f);
        dets[obase + 3] = fmaxf(pcy + 0.5f * ph - 1.0f, 0.0f);
        dets[obase + 4] = s;
        sv[(size_t)(b * RR + i) * CM1 + j] = 1.0f;
    }
}

// ---------------------------------------------------------------------------
// Kernel B: one wave (64 lanes) per row — softmax over 81 classes,
// max_scores = 1/sum(exp(x-max)), pred_labels = first argmax.
// ---------------------------------------------------------------------------
__global__ __launch_bounds__(256) void softmax_kernel(
    const float* __restrict__ cls,   // (B*R, 81)
    float* __restrict__ dist,        // (B*R, 81)
    float* __restrict__ maxs,        // (B*R,)
    float* __restrict__ labels)      // (B*R,)
{
    const int wave = threadIdx.x >> 6;
    const int lane = threadIdx.x & 63;
    const int row  = blockIdx.x * 4 + wave;
    if (row >= BB * RR) return;

    const float* in = cls + (size_t)row * CC;
    float v0 = in[lane];
    float v1 = (lane < CC - 64) ? in[64 + lane] : -INFINITY;

    float m  = v0;
    int   mi = lane;
    if (v1 > m) { m = v1; mi = 64 + lane; }

    for (int off = 32; off > 0; off >>= 1) {
        float om  = __shfl_xor(m, off);
        int   omi = __shfl_xor(mi, off);
        if (om > m || (om == m && omi < mi)) { m = om; mi = omi; }
    }

    float e0 = expf(v0 - m);
    float e1 = (lane < CC - 64) ? expf(v1 - m) : 0.0f;
    float s  = e0 + e1;
    for (int off = 32; off > 0; off >>= 1) s += __shfl_xor(s, off);

    float inv = 1.0f / s;
    float* out = dist + (size_t)row * CC;
    out[lane] = e0 * inv;
    if (lane < CC - 64) out[64 + lane] = e1 * inv;
    if (lane == 0) {
        maxs[row]   = inv;
        labels[row] = (float)mi;
    }
}

extern "C" void kernel_launch(void* const* d_in, const int* in_sizes, int n_in,
                              void* d_out, int out_size, void* d_ws, size_t ws_size,
                              hipStream_t stream) {
    const float* rois = (const float*)d_in[0];   // B*R*5
    const float* cls  = (const float*)d_in[1];   // B*R*81
    const float* bbox = (const float*)d_in[2];   // B*R*324

    float* out = (float*)d_out;
    const size_t dets_off = 0;
    const size_t sv_off   = (size_t)BB * RR * CM1 * 5;         // 25,600,000
    const size_t dist_off = sv_off + (size_t)BB * RR * CM1;    // 30,720,000
    const size_t maxs_off = dist_off + (size_t)BB * RR * CC;   // 35,904,000
    const size_t lab_off  = maxs_off + (size_t)BB * RR;        // 35,968,000

    float* dets   = out + dets_off;
    float* sv     = out + sv_off;
    float* dist   = out + dist_off;
    float* maxs   = out + maxs_off;
    float* labels = out + lab_off;

    // Zero dets + sorted_valid (the vast majority of entries stay zero).
    hipMemsetAsync(dets, 0, dist_off * sizeof(float), stream);

    sort_decode_kernel<<<BB * CM1, 256, 0, stream>>>(rois, cls, bbox, dets, sv);

    const int rows = BB * RR;
    softmax_kernel<<<(rows + 3) / 4, 256, 0, stream>>>(cls, dist, maxs, labels);
}

// Round 3
// 64.952 us; speedup vs baseline: 2.9504x; 1.1902x over previous
//
#include <hip/hip_runtime.h>
#include <hip/hip_bf16.h>
#include <math.h>

#define BB 32
#define RR 2000
#define CC 81
#define CM1 80

// ---------------------------------------------------------------------------
// Kernel A: per-(batch, class) column — compact valid entries, sort by
// (score desc, row asc), decode boxes for valid ranks, write ONLY the valid
// prefix of dets/sorted_valid (the rest is pre-zeroed by the fused kernel).
// ---------------------------------------------------------------------------
__global__ __launch_bounds__(256) void sort_decode_kernel(
    const float* __restrict__ rois,      // (B, R, 5)
    const float* __restrict__ cls,       // (B, R, C)
    const float* __restrict__ bbox,      // (B, R, 4*C)
    float* __restrict__ dets,            // (B, R, 80, 5)
    float* __restrict__ sv)              // (B, R, 80)
{
    __shared__ float ssc[2048];
    __shared__ int   sidx[2048];
    __shared__ int   scount;

    const int b   = blockIdx.x / CM1;
    const int j   = blockIdx.x % CM1;     // class-1 index (0..79)
    const int tid = threadIdx.x;
    const int cls_col = j + 1;

    if (tid == 0) scount = 0;
    __syncthreads();

    // Compact valid (score, row) pairs into LDS.
    for (int r = tid; r < RR; r += 256) {
        float s = cls[(size_t)(b * RR + r) * CC + cls_col];
        if (s > 0.1f) {
            int p = atomicAdd(&scount, 1);
            ssc[p]  = s;
            sidx[p] = r;
        }
    }
    __syncthreads();

    const int n = scount;

    if (n > 1) {
        int n2 = 1;
        while (n2 < n) n2 <<= 1;
        // Pad to pow2 with sentinels that sort last.
        for (int i = n + tid; i < n2; i += 256) {
            ssc[i]  = -INFINITY;
            sidx[i] = 0x7FFFFFFF;
        }
        __syncthreads();

        // Bitonic sort, overall descending by (score, -row).
        for (int k = 2; k <= n2; k <<= 1) {
            for (int jj = k >> 1; jj > 0; jj >>= 1) {
                for (int i = tid; i < n2; i += 256) {
                    int ixj = i ^ jj;
                    if (ixj > i) {
                        float si = ssc[i], sx = ssc[ixj];
                        int   ii = sidx[i], ix = sidx[ixj];
                        bool before = (si > sx) || (si == sx && ii < ix);
                        bool doswap = ((i & k) == 0) ? !before : before;
                        if (doswap) {
                            ssc[i] = sx; ssc[ixj] = si;
                            sidx[i] = ix; sidx[ixj] = ii;
                        }
                    }
                }
                __syncthreads();
            }
        }
    }

    // Write only the valid prefix (rest pre-zeroed).
    for (int i = tid; i < n; i += 256) {
        size_t obase = ((size_t)(b * RR + i) * CM1 + j) * 5;
        int   r = sidx[i];
        float s = ssc[i];
        const float* rp = rois + (size_t)(b * RR + r) * 5;
        float x1 = rp[1], y1 = rp[2], x2 = rp[3], y2 = rp[4];
        float w  = x2 - x1 + 1.0f;
        float h  = y2 - y1 + 1.0f;
        float cx = x1 + 0.5f * w;
        float cy = y1 + 0.5f * h;
        const float* dp = bbox + (size_t)(b * RR + r) * (4 * CC) + 4 * cls_col;
        float dx = dp[0] * 0.1f, dy = dp[1] * 0.1f;
        float dw = dp[2] * 0.2f, dh = dp[3] * 0.2f;
        float pcx = dx * w + cx;
        float pcy = dy * h + cy;
        float pw  = expf(dw) * w;
        float ph  = expf(dh) * h;
        dets[obase + 0] = fmaxf(pcx - 0.5f * pw, 0.0f);
        dets[obase + 1] = fmaxf(pcy - 0.5f * ph, 0.0f);
        dets[obase + 2] = fmaxf(pcx + 0.5f * pw - 1.0f, 0.0f);
        dets[obase + 3] = fmaxf(pcy + 0.5f * ph - 1.0f, 0.0f);
        dets[obase + 4] = s;
        sv[(size_t)(b * RR + i) * CM1 + j] = 1.0f;
    }
}

// ---------------------------------------------------------------------------
// Kernel B (fused): zero a 1920-float slice of dets+sv, then one wave per row
// softmax over 81 classes. 16,000 blocks x 256 threads covers both exactly:
//   zero: 16,000 * 480 float4 = 30,720,000 floats (dets 25.6M + sv 5.12M)
//   softmax: 16,000 * 4 waves = 64,000 rows
// ---------------------------------------------------------------------------
__global__ __launch_bounds__(256) void softmax_zero_kernel(
    const float* __restrict__ cls,   // (B*R, 81)
    float* __restrict__ dist,        // (B*R, 81)
    float* __restrict__ maxs,        // (B*R,)
    float* __restrict__ labels,      // (B*R,)
    float4* __restrict__ zbase)      // dets start (30,720,000 floats to zero)
{
    const int tid = threadIdx.x;

    // --- zero slice (issue stores first, they need no inputs) ---
    const float4 z4 = make_float4(0.0f, 0.0f, 0.0f, 0.0f);
    const int zb = blockIdx.x * 480;
    zbase[zb + tid] = z4;                       // 256
    if (tid < 224) zbase[zb + 256 + tid] = z4;  // 224  -> 480 total

    // --- softmax row ---
    const int wave = tid >> 6;
    const int lane = tid & 63;
    const int row  = blockIdx.x * 4 + wave;

    const float* in = cls + (size_t)row * CC;
    float v0 = in[lane];
    float v1 = (lane < CC - 64) ? in[64 + lane] : -INFINITY;

    float m  = v0;
    int   mi = lane;
    if (v1 > m) { m = v1; mi = 64 + lane; }

    for (int off = 32; off > 0; off >>= 1) {
        float om  = __shfl_xor(m, off);
        int   omi = __shfl_xor(mi, off);
        if (om > m || (om == m && omi < mi)) { m = om; mi = omi; }
    }

    float e0 = expf(v0 - m);
    float e1 = (lane < CC - 64) ? expf(v1 - m) : 0.0f;
    float s  = e0 + e1;
    for (int off = 32; off > 0; off >>= 1) s += __shfl_xor(s, off);

    float inv = 1.0f / s;
    float* out = dist + (size_t)row * CC;
    out[lane] = e0 * inv;
    if (lane < CC - 64) out[64 + lane] = e1 * inv;
    if (lane == 0) {
        maxs[row]   = inv;
        labels[row] = (float)mi;
    }
}

extern "C" void kernel_launch(void* const* d_in, const int* in_sizes, int n_in,
                              void* d_out, int out_size, void* d_ws, size_t ws_size,
                              hipStream_t stream) {
    const float* rois = (const float*)d_in[0];   // B*R*5
    const float* cls  = (const float*)d_in[1];   // B*R*81
    const float* bbox = (const float*)d_in[2];   // B*R*324

    float* out = (float*)d_out;
    const size_t dets_off = 0;
    const size_t sv_off   = (size_t)BB * RR * CM1 * 5;         // 25,600,000
    const size_t dist_off = sv_off + (size_t)BB * RR * CM1;    // 30,720,000
    const size_t maxs_off = dist_off + (size_t)BB * RR * CC;   // 35,904,000
    const size_t lab_off  = maxs_off + (size_t)BB * RR;        // 35,968,000

    float* dets   = out + dets_off;
    float* sv     = out + sv_off;
    float* dist   = out + dist_off;
    float* maxs   = out + maxs_off;
    float* labels = out + lab_off;

    // Fused: zero dets+sv (30.72M floats) + softmax/max/argmax.
    softmax_zero_kernel<<<(BB * RR) / 4, 256, 0, stream>>>(
        cls, dist, maxs, labels, (float4*)dets);

    // Then scatter the valid sorted detections into the zeroed region.
    sort_decode_kernel<<<BB * CM1, 256, 0, stream>>>(rois, cls, bbox, dets, sv);
}